// Round 2
// baseline (788.604 us; speedup 1.0000x reference)
//
#include <hip/hip_runtime.h>

// Fused MLP: x[131072,512] -> (Linear+LN+CELU)x4 -> spectral-norm head -> [131072,1]
// One block = 64 rows, full feature width in LDS between layers.
// GEMM1/2 bf16 MFMA (32x32x16) with IN-REGISTER fp32 LayerNorm (no pre-LN bf16
// quantization); GEMM3 split-precision bf16 (hi+lo for both operands); layer4+head fp32.

typedef unsigned short u16;
typedef unsigned int   u32;
typedef __bf16  bf16x8 __attribute__((ext_vector_type(8)));
typedef float   f32x16 __attribute__((ext_vector_type(16)));

__device__ __forceinline__ u16 f2bf(float f) {           // RTN-even f32->bf16
    u32 x = __builtin_bit_cast(u32, f);
    x += 0x7FFFu + ((x >> 16) & 1u);
    return (u16)(x >> 16);
}
__device__ __forceinline__ float bfval(u16 h) { return __builtin_bit_cast(float, (u32)h << 16); }
__device__ __forceinline__ float bfl(u32 v) { return __builtin_bit_cast(float, v << 16); }
__device__ __forceinline__ float bfh(u32 v) { return __builtin_bit_cast(float, v & 0xFFFF0000u); }
__device__ __forceinline__ u32 pack2(float a, float b) { return (u32)f2bf(a) | ((u32)f2bf(b) << 16); }
__device__ __forceinline__ float celu1(float x) { return x > 0.f ? x : __expf(x) - 1.f; }

// ---- param LDS offsets (floats) ----
#define PB1 0
#define PG1 512
#define PBE1 1024
#define PB2 1536
#define PG2 1664
#define PBE2 1792
#define PB3 1920
#define PG3 1952
#define PBE3 1984
#define PB4 2016
#define PG4 2024
#define PBE4 2032
#define PW4 2040
#define PWH 2296
#define PBH 2304
#define PU  2305
#define NPAR 2306

// ws element offsets (u16)
#define W1B_OFF 0
#define W2B_OFF 262144
#define W3B_OFF 327680
#define W3L_OFF 331776
#define PREP_N  335872

__global__ void prep_weights(const float* __restrict__ W1, const float* __restrict__ W2,
                             const float* __restrict__ W3, u16* __restrict__ wsb) {
    int i = blockIdx.x * 256 + threadIdx.x;   // grid sized exactly: 1312*256 == 335872
    float v;
    if (i < W2B_OFF)      v = W1[i];
    else if (i < W3B_OFF) v = W2[i - W2B_OFF];
    else if (i < W3L_OFF) v = W3[i - W3B_OFF];
    else {                                     // W3 low residual (split precision)
        float w = W3[i - W3L_OFF];
        wsb[i] = f2bf(w - bfval(f2bf(w)));
        return;
    }
    wsb[i] = f2bf(v);
}

__global__ __launch_bounds__(512, 2) void fused_mlp(
    const float* __restrict__ x,
    const u16* __restrict__ W1b, const u16* __restrict__ W2b,
    const u16* __restrict__ W3b, const u16* __restrict__ W3Lb,
    const float* __restrict__ b1, const float* __restrict__ g1, const float* __restrict__ be1,
    const float* __restrict__ b2, const float* __restrict__ g2, const float* __restrict__ be2,
    const float* __restrict__ b3, const float* __restrict__ g3, const float* __restrict__ be3,
    const float* __restrict__ W4, const float* __restrict__ b4, const float* __restrict__ g4,
    const float* __restrict__ be4,
    const float* __restrict__ Wh, const float* __restrict__ bh, const float* __restrict__ uvec,
    float* __restrict__ out)
{
    __shared__ __align__(16) u16 sA[64][72];     // x chunk, bf16 [64 rows][64k (+8 pad)]
    __shared__ __align__(16) u16 sH1[64][520];   // h1 post-act bf16 [64][512 (+8)]
    __shared__ __align__(16) u16 sH2[64][136];   // h2 post-act bf16 hi
    __shared__ __align__(16) u16 sH2L[64][136];  // h2 post-act bf16 lo residual
    __shared__ __align__(16) float sH3f[64][36]; // h3 post-act fp32 [64][32 (+4)]
    __shared__ __align__(16) float sPS[64][8];   // LN partial sums / reused as h4 [64][8]
    __shared__ __align__(16) float sPQ[64][8];   // LN partial sumsq
    __shared__ float sMu[64], sRs[64];
    __shared__ __align__(16) float sP[NPAR + 2]; // staged params

    const int tid = threadIdx.x;
    const int row0 = blockIdx.x * 64;
    const int wv = tid >> 6;          // wave 0..7
    const int lane = tid & 63;
    const int ln = lane & 31;
    const int lh = lane >> 5;

    // ---- stage small params into LDS ----
    for (int i = tid; i < NPAR; i += 512) {
        float v;
        if      (i < 512)  v = b1[i];
        else if (i < 1024) v = g1[i - 512];
        else if (i < 1536) v = be1[i - 1024];
        else if (i < 1664) v = b2[i - 1536];
        else if (i < 1792) v = g2[i - 1664];
        else if (i < 1920) v = be2[i - 1792];
        else if (i < 1952) v = b3[i - 1920];
        else if (i < 1984) v = g3[i - 1952];
        else if (i < 2016) v = be3[i - 1984];
        else if (i < 2024) v = b4[i - 2016];
        else if (i < 2032) v = g4[i - 2024];
        else if (i < 2040) v = be4[i - 2032];
        else if (i < 2296) v = W4[i - 2040];
        else if (i < 2304) v = Wh[i - 2296];
        else if (i == 2304) v = bh[0];
        else                v = uvec[0];
        sP[i] = v;
    }

    // ================= GEMM1: h1 = x @ W1^T  (M=64,N=512,K=512) =================
    const int Mt = wv >> 2;           // M-tile 0..1
    const int Ng = wv & 3;            // N-group (128 cols)

    // staging map: thread -> 8 consecutive floats of x
    const int sr = tid >> 3;          // 0..63
    const int sc = (tid & 7) * 8;     // 0..56
    const float* xrow = x + (long)(row0 + sr) * 512 + sc;

    // 2-deep x prefetch (covers HBM latency)
    float4 pa0 = *(const float4*)(xrow);
    float4 pa1 = *(const float4*)(xrow + 4);
    float4 pb0 = *(const float4*)(xrow + 64);
    float4 pb1 = *(const float4*)(xrow + 68);

    // B fragment base: W1b[n*512 + k], n = Ng*128 + nt*32 + ln, k = ksg*16 + lh*8
    const u16* wp = W1b + (long)ln * 512 + lh * 8;
    bf16x8 bfr[4];
#pragma unroll
    for (int nt = 0; nt < 4; ++nt)
        bfr[nt] = *(const bf16x8*)(wp + (long)((Ng * 4 + nt) * 32) * 512);

    f32x16 acc[4] = {};

    for (int c = 0; c < 8; ++c) {
        __syncthreads();              // sA consumers of prev chunk done (also covers sP staging)
        {   // write prefetched chunk c (alternating register set)
            float4 q0 = (c & 1) ? pb0 : pa0;
            float4 q1 = (c & 1) ? pb1 : pa1;
            uint4 wv4;
            wv4.x = pack2(q0.x, q0.y);
            wv4.y = pack2(q0.z, q0.w);
            wv4.z = pack2(q1.x, q1.y);
            wv4.w = pack2(q1.z, q1.w);
            *(uint4*)(&sA[sr][sc]) = wv4;
        }
        __syncthreads();
        if (c + 2 < 8) {              // refill the set just consumed with chunk c+2
            const float* nx = xrow + (c + 2) * 64;
            if (c & 1) { pb0 = *(const float4*)(nx); pb1 = *(const float4*)(nx + 4); }
            else       { pa0 = *(const float4*)(nx); pa1 = *(const float4*)(nx + 4); }
        }
#pragma unroll
        for (int ks = 0; ks < 4; ++ks) {
            const int ksg = c * 4 + ks;
            bf16x8 af = *(const bf16x8*)(&sA[Mt * 32 + ln][ks * 16 + lh * 8]);
            bf16x8 nb0, nb1, nb2, nb3;
            const bool pre = (ksg < 31);
            if (pre) {
                const u16* np = wp + (ksg + 1) * 16;
                nb0 = *(const bf16x8*)(np + (long)((Ng * 4 + 0) * 32) * 512);
                nb1 = *(const bf16x8*)(np + (long)((Ng * 4 + 1) * 32) * 512);
                nb2 = *(const bf16x8*)(np + (long)((Ng * 4 + 2) * 32) * 512);
                nb3 = *(const bf16x8*)(np + (long)((Ng * 4 + 3) * 32) * 512);
            }
            acc[0] = __builtin_amdgcn_mfma_f32_32x32x16_bf16(af, bfr[0], acc[0], 0, 0, 0);
            acc[1] = __builtin_amdgcn_mfma_f32_32x32x16_bf16(af, bfr[1], acc[1], 0, 0, 0);
            acc[2] = __builtin_amdgcn_mfma_f32_32x32x16_bf16(af, bfr[2], acc[2], 0, 0, 0);
            acc[3] = __builtin_amdgcn_mfma_f32_32x32x16_bf16(af, bfr[3], acc[3], 0, 0, 0);
            if (pre) { bfr[0] = nb0; bfr[1] = nb1; bfr[2] = nb2; bfr[3] = nb3; }
        }
    }

    // ---- LN1 fully in-register (fp32): fold bias, butterfly row sums, apply ----
    // C/D: col=lane&31, row=(reg&3)+8*(reg>>2)+4*(lane>>5)
#pragma unroll
    for (int nt = 0; nt < 4; ++nt) {
        const float bb = sP[PB1 + (Ng * 4 + nt) * 32 + ln];
#pragma unroll
        for (int rg = 0; rg < 16; ++rg) acc[nt][rg] += bb;
    }
#pragma unroll
    for (int rg = 0; rg < 16; ++rg) {
        float s = acc[0][rg] + acc[1][rg] + acc[2][rg] + acc[3][rg];
        float q = acc[0][rg] * acc[0][rg] + acc[1][rg] * acc[1][rg]
                + acc[2][rg] * acc[2][rg] + acc[3][rg] * acc[3][rg];
#pragma unroll
        for (int m = 1; m < 32; m <<= 1) { s += __shfl_xor(s, m, 64); q += __shfl_xor(q, m, 64); }
        if (ln == 0) {
            const int row = Mt * 32 + (rg & 3) + 8 * (rg >> 2) + 4 * lh;
            sPS[row][Ng] = s; sPQ[row][Ng] = q;
        }
    }
    __syncthreads();
    if (tid < 64) {
        float s = sPS[tid][0] + sPS[tid][1] + sPS[tid][2] + sPS[tid][3];
        float q = sPQ[tid][0] + sPQ[tid][1] + sPQ[tid][2] + sPQ[tid][3];
        const float mu = s * (1.f / 512.f);
        const float var = q * (1.f / 512.f) - mu * mu;
        sMu[tid] = mu; sRs[tid] = rsqrtf(var + 1e-5f);
    }
    __syncthreads();
    {
        float gg[4], ee[4];
#pragma unroll
        for (int nt = 0; nt < 4; ++nt) {
            const int col = (Ng * 4 + nt) * 32 + ln;
            gg[nt] = sP[PG1 + col]; ee[nt] = sP[PBE1 + col];
        }
#pragma unroll
        for (int rg = 0; rg < 16; ++rg) {
            const int row = Mt * 32 + (rg & 3) + 8 * (rg >> 2) + 4 * lh;
            const float mu = sMu[row], rs = sRs[row];
#pragma unroll
            for (int nt = 0; nt < 4; ++nt) {
                const int col = (Ng * 4 + nt) * 32 + ln;
                const float hn = (acc[nt][rg] - mu) * rs * gg[nt] + ee[nt];
                sH1[row][col] = f2bf(celu1(hn));
            }
        }
    }
    __syncthreads();

    // ================= GEMM2: h2 = h1 @ W2^T (M=64,N=128,K=512), 1 tile/wave =================
    float v2[16];
    {
        const int Mt2 = wv >> 2;      // 0..1
        const int Nt2 = wv & 3;       // 0..3 (32-col tiles)
        f32x16 a2 = {}, a2b = {};
        const u16* w2p = W2b + (long)(Nt2 * 32 + ln) * 512 + lh * 8;
        const u16* h1p = &sH1[Mt2 * 32 + ln][lh * 8];
#pragma unroll
        for (int ks = 0; ks < 32; ks += 2) {
            bf16x8 af0 = *(const bf16x8*)(h1p + ks * 16);
            bf16x8 bf0 = *(const bf16x8*)(w2p + ks * 16);
            a2 = __builtin_amdgcn_mfma_f32_32x32x16_bf16(af0, bf0, a2, 0, 0, 0);
            bf16x8 af1 = *(const bf16x8*)(h1p + (ks + 1) * 16);
            bf16x8 bf1 = *(const bf16x8*)(w2p + (ks + 1) * 16);
            a2b = __builtin_amdgcn_mfma_f32_32x32x16_bf16(af1, bf1, a2b, 0, 0, 0);
        }
        const float bb = sP[PB2 + Nt2 * 32 + ln];
#pragma unroll
        for (int rg = 0; rg < 16; ++rg) v2[rg] = a2[rg] + a2b[rg] + bb;
        // LN2 partials in-register
#pragma unroll
        for (int rg = 0; rg < 16; ++rg) {
            float s = v2[rg], q = v2[rg] * v2[rg];
#pragma unroll
            for (int m = 1; m < 32; m <<= 1) { s += __shfl_xor(s, m, 64); q += __shfl_xor(q, m, 64); }
            if (ln == 0) {
                const int row = Mt2 * 32 + (rg & 3) + 8 * (rg >> 2) + 4 * lh;
                sPS[row][Nt2] = s; sPQ[row][Nt2] = q;
            }
        }
    }
    __syncthreads();
    if (tid < 64) {
        float s = sPS[tid][0] + sPS[tid][1] + sPS[tid][2] + sPS[tid][3];
        float q = sPQ[tid][0] + sPQ[tid][1] + sPQ[tid][2] + sPQ[tid][3];
        const float mu = s * (1.f / 128.f);
        const float var = q * (1.f / 128.f) - mu * mu;
        sMu[tid] = mu; sRs[tid] = rsqrtf(var + 1e-5f);
    }
    __syncthreads();
    {
        const int Mt2 = wv >> 2;
        const int Nt2 = wv & 3;
        const int col = Nt2 * 32 + ln;
        const float gg = sP[PG2 + col], ee = sP[PBE2 + col];
#pragma unroll
        for (int rg = 0; rg < 16; ++rg) {
            const int row = Mt2 * 32 + (rg & 3) + 8 * (rg >> 2) + 4 * lh;
            const float hn = (v2[rg] - sMu[row]) * sRs[row] * gg + ee;
            const float a = celu1(hn);
            const u16 hi = f2bf(a);
            sH2[row][col] = hi;
            sH2L[row][col] = f2bf(a - bfval(hi));   // lo residual for split GEMM3
        }
    }
    __syncthreads();

    // ===== GEMM3: h3 = h2 @ W3^T (M=64,N=32,K=128), split-precision, waves 0-1 =====
    if (wv < 2) {
        f32x16 a3 = {};
        const u16* w3p  = W3b  + (long)ln * 128 + lh * 8;
        const u16* w3lp = W3Lb + (long)ln * 128 + lh * 8;
        const u16* h2p  = &sH2 [wv * 32 + ln][lh * 8];
        const u16* h2lp = &sH2L[wv * 32 + ln][lh * 8];
#pragma unroll
        for (int ks = 0; ks < 8; ++ks) {
            bf16x8 fa_h = *(const bf16x8*)(h2p  + ks * 16);
            bf16x8 fa_l = *(const bf16x8*)(h2lp + ks * 16);
            bf16x8 fb_h = *(const bf16x8*)(w3p  + ks * 16);
            bf16x8 fb_l = *(const bf16x8*)(w3lp + ks * 16);
            a3 = __builtin_amdgcn_mfma_f32_32x32x16_bf16(fa_h, fb_h, a3, 0, 0, 0);
            a3 = __builtin_amdgcn_mfma_f32_32x32x16_bf16(fa_h, fb_l, a3, 0, 0, 0);
            a3 = __builtin_amdgcn_mfma_f32_32x32x16_bf16(fa_l, fb_h, a3, 0, 0, 0);
        }
        // LN3 fully in-register (full 32-wide rows within the ln-group)
        const float bb = sP[PB3 + ln];
        const float g3v = sP[PG3 + ln], e3v = sP[PBE3 + ln];
#pragma unroll
        for (int rg = 0; rg < 16; ++rg) {
            const float v = a3[rg] + bb;
            float s = v, q = v * v;
#pragma unroll
            for (int m = 1; m < 32; m <<= 1) { s += __shfl_xor(s, m, 64); q += __shfl_xor(q, m, 64); }
            const float mu = s * (1.f / 32.f);
            const float rs = rsqrtf(q * (1.f / 32.f) - mu * mu + 1e-5f);
            const int row = wv * 32 + (rg & 3) + 8 * (rg >> 2) + 4 * lh;
            sH3f[row][ln] = celu1((v - mu) * rs * g3v + e3v);   // fp32, no quantization
        }
    }
    __syncthreads();

    // ================= Layer4 (fp32): h4 = h3 @ W4^T + b4 (width 8) =================
    if (tid < 256) {
        const int r = tid & 63, og = tid >> 6;   // og 0..3, 2 outputs each
        float h[32];
        const float4* hp = (const float4*)(&sH3f[r][0]);
#pragma unroll
        for (int j = 0; j < 8; ++j) {
            float4 t = hp[j];
            h[j * 4 + 0] = t.x; h[j * 4 + 1] = t.y; h[j * 4 + 2] = t.z; h[j * 4 + 3] = t.w;
        }
#pragma unroll
        for (int oo = 0; oo < 2; ++oo) {
            const int o = og * 2 + oo;
            float a = sP[PB4 + o];
            const float* w4 = &sP[PW4 + o * 32];
#pragma unroll
            for (int k = 0; k < 32; ++k) a += h[k] * w4[k];
            sPS[r][o] = a;    // sPS reused as h4 buffer
        }
    }
    __syncthreads();

    // ================= LN4 + CELU + spectral-norm head =================
    if (tid < 64) {
        float v[8];
        float s = 0.f, q = 0.f;
#pragma unroll
        for (int o = 0; o < 8; ++o) { v[o] = sPS[tid][o]; s += v[o]; q += v[o] * v[o]; }
        const float mu = s * 0.125f;
        const float var = q * 0.125f - mu * mu;
        const float rs = rsqrtf(var + 1e-5f);

        // spectral norm of Wh [1,8], one power iteration (u/v detached)
        float wh[8];
        const float u0 = sP[PU];
        float nv = 0.f;
#pragma unroll
        for (int o = 0; o < 8; ++o) { wh[o] = sP[PWH + o]; float t = wh[o] * u0; nv += t * t; }
        nv = sqrtf(nv);
        const float inv = 1.f / (nv + 1e-12f);
        float s2 = 0.f;
#pragma unroll
        for (int o = 0; o < 8; ++o) s2 += wh[o] * (wh[o] * u0 * inv);
        const float u2 = s2 / (fabsf(s2) + 1e-12f);
        const float sigma = u2 * s2;
        const float isg = 1.f / sigma;

        float y = sP[PBH];
#pragma unroll
        for (int o = 0; o < 8; ++o) {
            const float hn = (v[o] - mu) * rs * sP[PG4 + o] + sP[PBE4 + o];
            y += celu1(hn) * wh[o] * isg;
        }
        out[row0 + tid] = y;
    }
}

extern "C" void kernel_launch(void* const* d_in, const int* in_sizes, int n_in,
                              void* d_out, int out_size, void* d_ws, size_t ws_size,
                              hipStream_t stream) {
    const float* x   = (const float*)d_in[0];
    const float* W1  = (const float*)d_in[1];
    const float* b1  = (const float*)d_in[2];
    const float* g1  = (const float*)d_in[3];
    const float* be1 = (const float*)d_in[4];
    const float* W2  = (const float*)d_in[5];
    const float* b2  = (const float*)d_in[6];
    const float* g2  = (const float*)d_in[7];
    const float* be2 = (const float*)d_in[8];
    const float* W3  = (const float*)d_in[9];
    const float* b3  = (const float*)d_in[10];
    const float* g3  = (const float*)d_in[11];
    const float* be3 = (const float*)d_in[12];
    const float* W4  = (const float*)d_in[13];
    const float* b4  = (const float*)d_in[14];
    const float* g4  = (const float*)d_in[15];
    const float* be4 = (const float*)d_in[16];
    const float* Wh  = (const float*)d_in[17];
    const float* bh  = (const float*)d_in[18];
    const float* u   = (const float*)d_in[19];
    float* out = (float*)d_out;
    u16* wsb = (u16*)d_ws;

    prep_weights<<<dim3(PREP_N / 256), dim3(256), 0, stream>>>(W1, W2, W3, wsb);

    const int rows = in_sizes[0] / 512;       // 131072
    fused_mlp<<<dim3(rows / 64), dim3(512), 0, stream>>>(
        x, wsb + W1B_OFF, wsb + W2B_OFF, wsb + W3B_OFF, wsb + W3L_OFF,
        b1, g1, be1, b2, g2, be2, b3, g3, be3,
        W4, b4, g4, be4, Wh, bh, u, out);
}

// Round 3
// 604.933 us; speedup vs baseline: 1.3036x; 1.3036x over previous
//
#include <hip/hip_runtime.h>

// Fused MLP: x[131072,512] -> (Linear+LN+CELU)x4 -> spectral-norm head -> [131072,1]
// One block = 64 rows, full feature width in LDS between layers.
// R3: weights pre-packed into MFMA-fragment order so every B-operand load is a
// single coalesced 1KB burst (16B/lane x 64 lanes); 3-4 deep register prefetch.
// GEMM1/2 bf16 MFMA (32x32x16) with in-register fp32 LayerNorm; GEMM3
// split-precision bf16 (hi+lo both operands); layer4+head fp32.

typedef unsigned short u16;
typedef unsigned int   u32;
typedef __bf16  bf16x8 __attribute__((ext_vector_type(8)));
typedef float   f32x16 __attribute__((ext_vector_type(16)));

__device__ __forceinline__ u16 f2bf(float f) {           // RTN-even f32->bf16
    u32 x = __builtin_bit_cast(u32, f);
    x += 0x7FFFu + ((x >> 16) & 1u);
    return (u16)(x >> 16);
}
__device__ __forceinline__ float bfval(u16 h) { return __builtin_bit_cast(float, (u32)h << 16); }
__device__ __forceinline__ u32 pack2(float a, float b) { return (u32)f2bf(a) | ((u32)f2bf(b) << 16); }
__device__ __forceinline__ float celu1(float x) { return x > 0.f ? x : __expf(x) - 1.f; }

// ---- param LDS offsets (floats) ----
#define PB1 0
#define PG1 512
#define PBE1 1024
#define PB2 1536
#define PG2 1664
#define PBE2 1792
#define PB3 1920
#define PG3 1952
#define PBE3 1984
#define PB4 2016
#define PG4 2024
#define PBE4 2032
#define PW4 2040
#define PWH 2296
#define PBH 2304
#define PU  2305
#define NPAR 2306

// ws element offsets (u16), fragment-packed layouts:
// W1F: [ksg 0..32)[ntile 0..16)[lane 0..64)[e 0..8)   (n = ntile*32+(lane&31), k = ksg*16+(lane>>5)*8+e)
// W2F: [ksg 0..32)[ntile 0..4 )[lane][e]
// W3F/W3LF: [ksg 0..8)[lane][e]  (hi / lo-residual)
#define W1F_OFF 0
#define W2F_OFF 262144
#define W3F_OFF 327680
#define W3LF_OFF 331776
#define NGROUPS 41984     // total fragment groups of 8 elements

__global__ void prep_weights(const float* __restrict__ W1, const float* __restrict__ W2,
                             const float* __restrict__ W3, u16* __restrict__ wsb) {
    const int g = blockIdx.x * 256 + threadIdx.x;   // 164*256 == 41984 exactly
    if (g < 32768) {                                // W1 fragments
        const int l = g & 63, t = (g >> 6) & 15, ksg = g >> 10;
        const int n = t * 32 + (l & 31);
        const int k0 = ksg * 16 + (l >> 5) * 8;
        u16* dst = wsb + W1F_OFF + g * 8;
        const float* src = W1 + n * 512 + k0;
#pragma unroll
        for (int e = 0; e < 8; ++e) dst[e] = f2bf(src[e]);
    } else if (g < 40960) {                         // W2 fragments
        const int h = g - 32768;
        const int l = h & 63, t = (h >> 6) & 3, ksg = h >> 8;
        const int n = t * 32 + (l & 31);
        const int k0 = ksg * 16 + (l >> 5) * 8;
        u16* dst = wsb + W2F_OFF + h * 8;
        const float* src = W2 + n * 512 + k0;
#pragma unroll
        for (int e = 0; e < 8; ++e) dst[e] = f2bf(src[e]);
    } else if (g < 41472) {                         // W3 hi fragments
        const int h = g - 40960;
        const int l = h & 63, ksg = h >> 6;
        const int n = l & 31;
        const int k0 = ksg * 16 + (l >> 5) * 8;
        u16* dst = wsb + W3F_OFF + h * 8;
        const float* src = W3 + n * 128 + k0;
#pragma unroll
        for (int e = 0; e < 8; ++e) dst[e] = f2bf(src[e]);
    } else {                                        // W3 lo-residual fragments
        const int h = g - 41472;
        const int l = h & 63, ksg = h >> 6;
        const int n = l & 31;
        const int k0 = ksg * 16 + (l >> 5) * 8;
        u16* dst = wsb + W3LF_OFF + h * 8;
        const float* src = W3 + n * 128 + k0;
#pragma unroll
        for (int e = 0; e < 8; ++e) { float w = src[e]; dst[e] = f2bf(w - bfval(f2bf(w))); }
    }
}

__global__ __launch_bounds__(512, 2) void fused_mlp(
    const float* __restrict__ x,
    const u16* __restrict__ W1b, const u16* __restrict__ W2b,
    const u16* __restrict__ W3b, const u16* __restrict__ W3Lb,
    const float* __restrict__ b1, const float* __restrict__ g1, const float* __restrict__ be1,
    const float* __restrict__ b2, const float* __restrict__ g2, const float* __restrict__ be2,
    const float* __restrict__ b3, const float* __restrict__ g3, const float* __restrict__ be3,
    const float* __restrict__ W4, const float* __restrict__ b4, const float* __restrict__ g4,
    const float* __restrict__ be4,
    const float* __restrict__ Wh, const float* __restrict__ bh, const float* __restrict__ uvec,
    float* __restrict__ out)
{
    __shared__ __align__(16) u16 sA[64][72];     // x chunk, bf16 [64 rows][64k (+8 pad)]
    __shared__ __align__(16) u16 sH1[64][520];   // h1 post-act bf16 [64][512 (+8)]
    __shared__ __align__(16) u16 sH2[64][136];   // h2 post-act bf16 hi
    __shared__ __align__(16) u16 sH2L[64][136];  // h2 post-act bf16 lo residual
    __shared__ __align__(16) float sH3f[64][36]; // h3 post-act fp32 [64][32 (+4)]
    __shared__ __align__(16) float sPS[64][8];   // LN partial sums / reused as h4 [64][8]
    __shared__ __align__(16) float sPQ[64][8];   // LN partial sumsq
    __shared__ float sMu[64], sRs[64];
    __shared__ __align__(16) float sP[NPAR + 2]; // staged params

    const int tid = threadIdx.x;
    const int row0 = blockIdx.x * 64;
    const int wv = tid >> 6;          // wave 0..7
    const int lane = tid & 63;
    const int ln = lane & 31;
    const int lh = lane >> 5;

    // ---- stage small params into LDS (consumed only after GEMM1's barriers) ----
    for (int i = tid; i < NPAR; i += 512) {
        float v;
        if      (i < 512)  v = b1[i];
        else if (i < 1024) v = g1[i - 512];
        else if (i < 1536) v = be1[i - 1024];
        else if (i < 1664) v = b2[i - 1536];
        else if (i < 1792) v = g2[i - 1664];
        else if (i < 1920) v = be2[i - 1792];
        else if (i < 1952) v = b3[i - 1920];
        else if (i < 1984) v = g3[i - 1952];
        else if (i < 2016) v = be3[i - 1984];
        else if (i < 2024) v = b4[i - 2016];
        else if (i < 2032) v = g4[i - 2024];
        else if (i < 2040) v = be4[i - 2032];
        else if (i < 2296) v = W4[i - 2040];
        else if (i < 2304) v = Wh[i - 2296];
        else if (i == 2304) v = bh[0];
        else                v = uvec[0];
        sP[i] = v;
    }

    // ================= GEMM1: h1 = x @ W1^T  (M=64,N=512,K=512) =================
    const int Mt = wv >> 2;           // M-tile 0..1
    const int Ng = wv & 3;            // N-group (128 cols)

    // staging map: thread -> 8 consecutive floats of x
    const int sr = tid >> 3;          // 0..63
    const int sc = (tid & 7) * 8;     // 0..56
    const float* xrow = x + (long)(row0 + sr) * 512 + sc;

    // 2-deep x prefetch (covers HBM latency)
    float4 pa0 = *(const float4*)(xrow);
    float4 pa1 = *(const float4*)(xrow + 4);
    float4 pb0 = *(const float4*)(xrow + 64);
    float4 pb1 = *(const float4*)(xrow + 68);

    // fragment-packed W1: frag(ksg,nt) at wq + ksg*8192 + nt*512, coalesced 1KB/wave
    const u16* wq = W1b + (Ng * 4) * 512 + lane * 8;
    bf16x8 Bf[4][4];                  // 3-deep rotating prefetch (slot = ksg&3)
#pragma unroll
    for (int s = 0; s < 3; ++s)
#pragma unroll
        for (int nt = 0; nt < 4; ++nt)
            Bf[s][nt] = *(const bf16x8*)(wq + s * 8192 + nt * 512);

    f32x16 acc[4] = {};

#pragma unroll
    for (int c = 0; c < 8; ++c) {
        __syncthreads();              // sA consumers of prev chunk done
        {   // write prefetched chunk c (alternating register set)
            float4 q0 = (c & 1) ? pb0 : pa0;
            float4 q1 = (c & 1) ? pb1 : pa1;
            uint4 wv4;
            wv4.x = pack2(q0.x, q0.y);
            wv4.y = pack2(q0.z, q0.w);
            wv4.z = pack2(q1.x, q1.y);
            wv4.w = pack2(q1.z, q1.w);
            *(uint4*)(&sA[sr][sc]) = wv4;
        }
        __syncthreads();
        if (c + 2 < 8) {              // refill the set just consumed with chunk c+2
            const float* nx = xrow + (c + 2) * 64;
            if (c & 1) { pb0 = *(const float4*)(nx); pb1 = *(const float4*)(nx + 4); }
            else       { pa0 = *(const float4*)(nx); pa1 = *(const float4*)(nx + 4); }
        }
#pragma unroll
        for (int ks = 0; ks < 4; ++ks) {
            const int ksg = c * 4 + ks;
            const int slot = ksg & 3;
            if (ksg + 3 < 32) {       // prefetch 3 ahead into the slot freed 1 iter ago
                const int ps = (ksg + 3) & 3;
                const u16* np = wq + (ksg + 3) * 8192;
                Bf[ps][0] = *(const bf16x8*)(np);
                Bf[ps][1] = *(const bf16x8*)(np + 512);
                Bf[ps][2] = *(const bf16x8*)(np + 1024);
                Bf[ps][3] = *(const bf16x8*)(np + 1536);
            }
            bf16x8 af = *(const bf16x8*)(&sA[Mt * 32 + ln][ks * 16 + lh * 8]);
            acc[0] = __builtin_amdgcn_mfma_f32_32x32x16_bf16(af, Bf[slot][0], acc[0], 0, 0, 0);
            acc[1] = __builtin_amdgcn_mfma_f32_32x32x16_bf16(af, Bf[slot][1], acc[1], 0, 0, 0);
            acc[2] = __builtin_amdgcn_mfma_f32_32x32x16_bf16(af, Bf[slot][2], acc[2], 0, 0, 0);
            acc[3] = __builtin_amdgcn_mfma_f32_32x32x16_bf16(af, Bf[slot][3], acc[3], 0, 0, 0);
        }
    }

    // ---- LN1 fully in-register (fp32): fold bias, butterfly row sums, apply ----
    // C/D: col=lane&31, row=(reg&3)+8*(reg>>2)+4*(lane>>5)
#pragma unroll
    for (int nt = 0; nt < 4; ++nt) {
        const float bb = sP[PB1 + (Ng * 4 + nt) * 32 + ln];
#pragma unroll
        for (int rg = 0; rg < 16; ++rg) acc[nt][rg] += bb;
    }
#pragma unroll
    for (int rg = 0; rg < 16; ++rg) {
        float s = acc[0][rg] + acc[1][rg] + acc[2][rg] + acc[3][rg];
        float q = acc[0][rg] * acc[0][rg] + acc[1][rg] * acc[1][rg]
                + acc[2][rg] * acc[2][rg] + acc[3][rg] * acc[3][rg];
#pragma unroll
        for (int m = 1; m < 32; m <<= 1) { s += __shfl_xor(s, m, 64); q += __shfl_xor(q, m, 64); }
        if (ln == 0) {
            const int row = Mt * 32 + (rg & 3) + 8 * (rg >> 2) + 4 * lh;
            sPS[row][Ng] = s; sPQ[row][Ng] = q;
        }
    }
    __syncthreads();
    if (tid < 64) {
        float s = sPS[tid][0] + sPS[tid][1] + sPS[tid][2] + sPS[tid][3];
        float q = sPQ[tid][0] + sPQ[tid][1] + sPQ[tid][2] + sPQ[tid][3];
        const float mu = s * (1.f / 512.f);
        const float var = q * (1.f / 512.f) - mu * mu;
        sMu[tid] = mu; sRs[tid] = rsqrtf(var + 1e-5f);
    }
    __syncthreads();
    {
        float gg[4], ee[4];
#pragma unroll
        for (int nt = 0; nt < 4; ++nt) {
            const int col = (Ng * 4 + nt) * 32 + ln;
            gg[nt] = sP[PG1 + col]; ee[nt] = sP[PBE1 + col];
        }
#pragma unroll
        for (int rg = 0; rg < 16; ++rg) {
            const int row = Mt * 32 + (rg & 3) + 8 * (rg >> 2) + 4 * lh;
            const float mu = sMu[row], rs = sRs[row];
#pragma unroll
            for (int nt = 0; nt < 4; ++nt) {
                const int col = (Ng * 4 + nt) * 32 + ln;
                const float hn = (acc[nt][rg] - mu) * rs * gg[nt] + ee[nt];
                sH1[row][col] = f2bf(celu1(hn));
            }
        }
    }
    __syncthreads();

    // ================= GEMM2: h2 = h1 @ W2^T (M=64,N=128,K=512), 1 tile/wave =================
    float v2[16];
    {
        const int Mt2 = wv >> 2;      // 0..1
        const int Nt2 = wv & 3;       // 0..3 (32-col tiles)
        // fragment-packed W2: frag(ksg) at w2q + ksg*2048, coalesced 1KB/wave
        const u16* w2q = W2b + Nt2 * 512 + lane * 8;
        bf16x8 W2f[4];                // 4-deep rotating prefetch
#pragma unroll
        for (int s = 0; s < 4; ++s) W2f[s] = *(const bf16x8*)(w2q + s * 2048);

        f32x16 a2 = {}, a2b = {};
        const u16* h1p = &sH1[Mt2 * 32 + ln][lh * 8];
#pragma unroll
        for (int ksg = 0; ksg < 32; ++ksg) {
            const int slot = ksg & 3;
            bf16x8 af = *(const bf16x8*)(h1p + ksg * 16);
            if (ksg & 1) a2b = __builtin_amdgcn_mfma_f32_32x32x16_bf16(af, W2f[slot], a2b, 0, 0, 0);
            else         a2  = __builtin_amdgcn_mfma_f32_32x32x16_bf16(af, W2f[slot], a2, 0, 0, 0);
            if (ksg + 4 < 32) W2f[slot] = *(const bf16x8*)(w2q + (ksg + 4) * 2048);
        }
        const float bb = sP[PB2 + Nt2 * 32 + ln];
#pragma unroll
        for (int rg = 0; rg < 16; ++rg) v2[rg] = a2[rg] + a2b[rg] + bb;
        // LN2 partials in-register
#pragma unroll
        for (int rg = 0; rg < 16; ++rg) {
            float s = v2[rg], q = v2[rg] * v2[rg];
#pragma unroll
            for (int m = 1; m < 32; m <<= 1) { s += __shfl_xor(s, m, 64); q += __shfl_xor(q, m, 64); }
            if (ln == 0) {
                const int row = Mt2 * 32 + (rg & 3) + 8 * (rg >> 2) + 4 * lh;
                sPS[row][Nt2] = s; sPQ[row][Nt2] = q;
            }
        }
    }
    __syncthreads();
    if (tid < 64) {
        float s = sPS[tid][0] + sPS[tid][1] + sPS[tid][2] + sPS[tid][3];
        float q = sPQ[tid][0] + sPQ[tid][1] + sPQ[tid][2] + sPQ[tid][3];
        const float mu = s * (1.f / 128.f);
        const float var = q * (1.f / 128.f) - mu * mu;
        sMu[tid] = mu; sRs[tid] = rsqrtf(var + 1e-5f);
    }
    __syncthreads();
    {
        const int Mt2 = wv >> 2;
        const int Nt2 = wv & 3;
        const int col = Nt2 * 32 + ln;
        const float gg = sP[PG2 + col], ee = sP[PBE2 + col];
#pragma unroll
        for (int rg = 0; rg < 16; ++rg) {
            const int row = Mt2 * 32 + (rg & 3) + 8 * (rg >> 2) + 4 * lh;
            const float hn = (v2[rg] - sMu[row]) * sRs[row] * gg + ee;
            const float a = celu1(hn);
            const u16 hi = f2bf(a);
            sH2[row][col] = hi;
            sH2L[row][col] = f2bf(a - bfval(hi));   // lo residual for split GEMM3
        }
    }
    __syncthreads();

    // ===== GEMM3: h3 = h2 @ W3^T (M=64,N=32,K=128), split-precision, waves 0-1 =====
    if (wv < 2) {
        f32x16 a3 = {};
        // fragment-packed W3: frag(ksg) at +ksg*512 (hi) / same (lo)
        const u16* w3q  = W3b  + lane * 8;
        const u16* w3lq = W3Lb + lane * 8;
        const u16* h2p  = &sH2 [wv * 32 + ln][lh * 8];
        const u16* h2lp = &sH2L[wv * 32 + ln][lh * 8];
#pragma unroll
        for (int ks = 0; ks < 8; ++ks) {
            bf16x8 fa_h = *(const bf16x8*)(h2p  + ks * 16);
            bf16x8 fa_l = *(const bf16x8*)(h2lp + ks * 16);
            bf16x8 fb_h = *(const bf16x8*)(w3q  + ks * 512);
            bf16x8 fb_l = *(const bf16x8*)(w3lq + ks * 512);
            a3 = __builtin_amdgcn_mfma_f32_32x32x16_bf16(fa_h, fb_h, a3, 0, 0, 0);
            a3 = __builtin_amdgcn_mfma_f32_32x32x16_bf16(fa_h, fb_l, a3, 0, 0, 0);
            a3 = __builtin_amdgcn_mfma_f32_32x32x16_bf16(fa_l, fb_h, a3, 0, 0, 0);
        }
        // LN3 fully in-register (full 32-wide rows within the ln-group)
        const float bb = sP[PB3 + ln];
        const float g3v = sP[PG3 + ln], e3v = sP[PBE3 + ln];
#pragma unroll
        for (int rg = 0; rg < 16; ++rg) {
            const float v = a3[rg] + bb;
            float s = v, q = v * v;
#pragma unroll
            for (int m = 1; m < 32; m <<= 1) { s += __shfl_xor(s, m, 64); q += __shfl_xor(q, m, 64); }
            const float mu = s * (1.f / 32.f);
            const float rs = rsqrtf(q * (1.f / 32.f) - mu * mu + 1e-5f);
            const int row = wv * 32 + (rg & 3) + 8 * (rg >> 2) + 4 * lh;
            sH3f[row][ln] = celu1((v - mu) * rs * g3v + e3v);   // fp32, no quantization
        }
    }
    __syncthreads();

    // ================= Layer4 (fp32): h4 = h3 @ W4^T + b4 (width 8) =================
    if (tid < 256) {
        const int r = tid & 63, og = tid >> 6;   // og 0..3, 2 outputs each
        float h[32];
        const float4* hp = (const float4*)(&sH3f[r][0]);
#pragma unroll
        for (int j = 0; j < 8; ++j) {
            float4 t = hp[j];
            h[j * 4 + 0] = t.x; h[j * 4 + 1] = t.y; h[j * 4 + 2] = t.z; h[j * 4 + 3] = t.w;
        }
#pragma unroll
        for (int oo = 0; oo < 2; ++oo) {
            const int o = og * 2 + oo;
            float a = sP[PB4 + o];
            const float* w4 = &sP[PW4 + o * 32];
#pragma unroll
            for (int k = 0; k < 32; ++k) a += h[k] * w4[k];
            sPS[r][o] = a;    // sPS reused as h4 buffer
        }
    }
    __syncthreads();

    // ================= LN4 + CELU + spectral-norm head =================
    if (tid < 64) {
        float v[8];
        float s = 0.f, q = 0.f;
#pragma unroll
        for (int o = 0; o < 8; ++o) { v[o] = sPS[tid][o]; s += v[o]; q += v[o] * v[o]; }
        const float mu = s * 0.125f;
        const float var = q * 0.125f - mu * mu;
        const float rs = rsqrtf(var + 1e-5f);

        // spectral norm of Wh [1,8], one power iteration (u/v detached)
        float wh[8];
        const float u0 = sP[PU];
        float nv = 0.f;
#pragma unroll
        for (int o = 0; o < 8; ++o) { wh[o] = sP[PWH + o]; float t = wh[o] * u0; nv += t * t; }
        nv = sqrtf(nv);
        const float inv = 1.f / (nv + 1e-12f);
        float s2 = 0.f;
#pragma unroll
        for (int o = 0; o < 8; ++o) s2 += wh[o] * (wh[o] * u0 * inv);
        const float u2 = s2 / (fabsf(s2) + 1e-12f);
        const float sigma = u2 * s2;
        const float isg = 1.f / sigma;

        float y = sP[PBH];
#pragma unroll
        for (int o = 0; o < 8; ++o) {
            const float hn = (v[o] - mu) * rs * sP[PG4 + o] + sP[PBE4 + o];
            y += celu1(hn) * wh[o] * isg;
        }
        out[row0 + tid] = y;
    }
}

extern "C" void kernel_launch(void* const* d_in, const int* in_sizes, int n_in,
                              void* d_out, int out_size, void* d_ws, size_t ws_size,
                              hipStream_t stream) {
    const float* x   = (const float*)d_in[0];
    const float* W1  = (const float*)d_in[1];
    const float* b1  = (const float*)d_in[2];
    const float* g1  = (const float*)d_in[3];
    const float* be1 = (const float*)d_in[4];
    const float* W2  = (const float*)d_in[5];
    const float* b2  = (const float*)d_in[6];
    const float* g2  = (const float*)d_in[7];
    const float* be2 = (const float*)d_in[8];
    const float* W3  = (const float*)d_in[9];
    const float* b3  = (const float*)d_in[10];
    const float* g3  = (const float*)d_in[11];
    const float* be3 = (const float*)d_in[12];
    const float* W4  = (const float*)d_in[13];
    const float* b4  = (const float*)d_in[14];
    const float* g4  = (const float*)d_in[15];
    const float* be4 = (const float*)d_in[16];
    const float* Wh  = (const float*)d_in[17];
    const float* bh  = (const float*)d_in[18];
    const float* u   = (const float*)d_in[19];
    float* out = (float*)d_out;
    u16* wsb = (u16*)d_ws;

    prep_weights<<<dim3(NGROUPS / 256), dim3(256), 0, stream>>>(W1, W2, W3, wsb);

    const int rows = in_sizes[0] / 512;       // 131072
    fused_mlp<<<dim3(rows / 64), dim3(512), 0, stream>>>(
        x, wsb + W1F_OFF, wsb + W2F_OFF, wsb + W3F_OFF, wsb + W3LF_OFF,
        b1, g1, be1, b2, g2, be2, b3, g3, be3,
        W4, b4, g4, be4, Wh, bh, u, out);
}